// Round 15
// baseline (1234.926 us; speedup 1.0000x reference)
//
#include <hip/hip_runtime.h>
#include <stdint.h>

#define H 256
#define NATOMS 100000
#define MB 32
#define NBLK (NATOMS / MB)   // 3125

typedef float floatx4 __attribute__((ext_vector_type(4)));
typedef short short8 __attribute__((ext_vector_type(8)));
typedef short short4v __attribute__((ext_vector_type(4)));

// lgkm-only barrier: global prefetches stay in flight across it.
#define BAR() do { asm volatile("s_waitcnt lgkmcnt(0)\n\ts_barrier" ::: "memory"); __builtin_amdgcn_sched_barrier(0); } while (0)

__device__ __forceinline__ unsigned short f2bf(float x) {
    union { float f; uint32_t u; } c; c.f = x;
    return (unsigned short)((c.u + 0x7FFFu + ((c.u >> 16) & 1u)) >> 16);
}
__device__ __forceinline__ float bf2f(unsigned short h) {
    union { uint32_t u; float f; } c; c.u = ((uint32_t)h) << 16; return c.f;
}
__device__ __forceinline__ uint32_t pk2(float lo, float hi) {
    return (uint32_t)f2bf(lo) | ((uint32_t)f2bf(hi) << 16);
}
__device__ __forceinline__ float upk(uint32_t u, int hi) {
    union { uint32_t u; float f; } c;
    c.u = hi ? (u & 0xFFFF0000u) : (u << 16);
    return c.f;
}

// ---------------------------------------------------------------------------
// Pack weights (f32 [K][N] row-major) into bf16 MFMA-B-fragment order.
// frag fl = nb*(K/32)+kb; lane l holds W[kb*32+(l>>4)*8+e][nb*16+(l&15)].
// ws layout (bf16 elems): U@0, V@65536, W1@131072, W2@262144 (896KB total).
// ---------------------------------------------------------------------------
__global__ void pack_weights(const float* __restrict__ U_W, const float* __restrict__ V_W,
                             const float* __restrict__ W1, const float* __restrict__ W2,
                             unsigned short* __restrict__ P) {
    int gtid = blockIdx.x * 256 + threadIdx.x;
    int fid = gtid >> 6, l = gtid & 63;
    const float* src; int K, N, fl; unsigned short* dst;
    if (fid < 128)      { src = U_W; K = 256; N = 256; fl = fid;       dst = P; }
    else if (fid < 256) { src = V_W; K = 256; N = 256; fl = fid - 128; dst = P + 65536; }
    else if (fid < 512) { src = W1;  K = 512; N = 256; fl = fid - 256; dst = P + 131072; }
    else                { src = W2;  K = 256; N = 768; fl = fid - 512; dst = P + 262144; }
    int kbc = K >> 5;
    int nb = fl / kbc, kb = fl - nb * kbc;
    int k0 = kb * 32 + ((l >> 4) << 3);
    int n0 = nb * 16 + (l & 15);
    short8 outv;
#pragma unroll
    for (int e = 0; e < 8; e++) outv[e] = (short)f2bf(src[(size_t)(k0 + e) * N + n0]);
    *(short8*)(dst + (size_t)fl * 512 + l * 8) = outv;
}

// ---------------------------------------------------------------------------
// Fused PaiNN mixing (R8 structure + whole-panel B prefetch, one pass ahead,
// + line-paired v_out stores). Block = 32 atoms, 512 thr (8 waves), LDS 64KB
// -> 2 blocks/CU (LDS-limited; VGPR budget at 4 waves/SIMD is 512 so panels
// fit in registers without touching occupancy). Wave w owns cols [32w,32w+32).
// A-frags 1KB MFMA-linear w/ kpos-XOR swizzle;
// lane read off loff = (l>>4)*256 + ((l15^(l>>4))<<4).
// LDS map: [0,48K) v-frags; post-B2 overlays [0,16K) Vv_norm->sdelta,
// [16,32K) hid; [48,64K) LNf s_norm frags.
// B-panels (16 x short8 = 64 VGPR each) are burst-loaded one full pass ahead:
// 16 outstanding L2 loads amortize ~300cyc latency to ~nothing per use.
// ---------------------------------------------------------------------------
__global__ __launch_bounds__(512, 4) void painn_main(
    const float* __restrict__ s, const float* __restrict__ v,
    const float* __restrict__ gamma, const float* __restrict__ beta,
    const float* __restrict__ b1, const float* __restrict__ b2,
    const unsigned short* __restrict__ P,
    float* __restrict__ s_out, float* __restrict__ v_out) {

    __shared__ unsigned short SH[32768];   // 64KB
    char* LB = (char*)SH;

    const int tid = threadIdx.x;
    const int w = tid >> 6, l = tid & 63;
    const int l15 = l & 15, lhi = l >> 4;
    const int loff = (lhi << 8) | ((l15 ^ lhi) << 4);
    const int atom0 = blockIdx.x * MB;
    const int aLN = tid >> 4, lg = tid & 15;          // 16 lanes per atom
    const int gLN = aLN >> 4, a15LN = aLN & 15;

    const short8* PU  = (const short8*)P;
    const short8* PV  = (const short8*)(P + 65536);
    const short8* PW1 = (const short8*)(P + 131072);
    const short8* PW2 = (const short8*)(P + 262144);

    // ---- stage v -> v-frags [0,48K) ----
    {
        const floatx4* vsrc = (const floatx4*)(v + (size_t)atom0 * 3 * H);
#pragma unroll
        for (int i = 0; i < 6; i++) {
            int p = i * 512 + tid;
            int a = p / 96, rem = p - a * 96;
            int d = rem >> 5, c8 = rem & 31;
            int q = ((a * 3 + d) << 6) + (c8 << 1);
            floatx4 x0 = vsrc[q], x1 = vsrc[q + 1];
            short8 pk;
#pragma unroll
            for (int j = 0; j < 4; j++) { pk[j] = (short)f2bf(x0[j]); pk[4 + j] = (short)f2bf(x1[j]); }
            int ks = c8 >> 2, kpos = c8 & 3;
            int bo = ((((a >> 4) * 24) + d * 8 + ks) << 10) + (kpos << 8) + (((a & 15) ^ kpos) << 4);
            *(short8*)(LB + bo) = pk;
        }
    }

    // ---- LayerNorm(s) -> LNf frags [48K,64K); raw s packed in regs ----
    short4v srp[4];
    {
        const floatx4* srow = (const floatx4*)(s + (size_t)(atom0 + aLN) * H);
        floatx4 vals[4];
        float sum = 0.f, sq = 0.f;
#pragma unroll
        for (int i = 0; i < 4; i++) {
            vals[i] = srow[lg + (i << 4)];
#pragma unroll
            for (int j = 0; j < 4; j++) { sum += vals[i][j]; sq += vals[i][j] * vals[i][j]; }
        }
#pragma unroll
        for (int m = 1; m < 16; m <<= 1) { sum += __shfl_xor(sum, m); sq += __shfl_xor(sq, m); }
        float mu = sum * (1.f / 256.f);
        float var = sq * (1.f / 256.f) - mu * mu;
        float rs = rsqrtf(var + 1e-5f);
#pragma unroll
        for (int i = 0; i < 4; i++) {
            int chunk = lg + (i << 4);
            floatx4 g4 = *(const floatx4*)(gamma + chunk * 4);
            floatx4 be4 = *(const floatx4*)(beta + chunk * 4);
            short4v pk, pr;
#pragma unroll
            for (int j = 0; j < 4; j++) {
                pk[j] = (short)f2bf((vals[i][j] - mu) * rs * g4[j] + be4[j]);
                pr[j] = (short)f2bf(vals[i][j]);
            }
            srp[i] = pr;
            int ks2 = chunk >> 3, kpos = (chunk >> 1) & 3, half = chunk & 1;
            int bo = 49152 + ((gLN * 8 + ks2) << 10) + (kpos << 8) + ((a15LN ^ kpos) << 4) + half * 8;
            *(short4v*)(LB + bo) = pk;
        }
    }

    // ---- p1 cf=0 panel burst (16 loads) before barrier ----
    short8 bU0[8], bV0[8];
#pragma unroll
    for (int ks = 0; ks < 8; ks++) {
        bU0[ks] = PU[(size_t)((w * 2) * 8 + ks) * 64 + l];
        bV0[ks] = PV[(size_t)((w * 2) * 8 + ks) * 64 + l];
    }

    BAR();  // B1: v-frags + LNf visible (vmcnt NOT drained)

    // ---- p1 cf=1 panel burst ----
    short8 bU1[8], bV1[8];
#pragma unroll
    for (int ks = 0; ks < 8; ks++) {
        bU1[ks] = PU[(size_t)((w * 2 + 1) * 8 + ks) * 64 + l];
        bV1[ks] = PV[(size_t)((w * 2 + 1) * 8 + ks) * 64 + l];
    }

    float dotv[2][2][4];
    uint32_t uvh[2][3][2][2];   // [cf][d][g][pair] packed bf16
    uint32_t nvp[2][2][2];      // [cf][g][pair]   packed bf16

    // ---- phase 1, cf = 0 ----
    {
        floatx4 accU[3][2], accV[3][2];
#pragma unroll
        for (int d = 0; d < 3; d++)
#pragma unroll
            for (int g = 0; g < 2; g++) { accU[d][g] = (floatx4)0.f; accV[d][g] = (floatx4)0.f; }
#pragma unroll
        for (int ks = 0; ks < 8; ks++) {
#pragma unroll
            for (int g = 0; g < 2; g++) {
                short8 af0 = *(const short8*)(LB + ((g * 24 + 0 * 8 + ks) << 10) + loff);
                short8 af1 = *(const short8*)(LB + ((g * 24 + 1 * 8 + ks) << 10) + loff);
                short8 af2 = *(const short8*)(LB + ((g * 24 + 2 * 8 + ks) << 10) + loff);
                __builtin_amdgcn_s_setprio(1);
                accU[0][g] = __builtin_amdgcn_mfma_f32_16x16x32_bf16(af0, bU0[ks], accU[0][g], 0, 0, 0);
                accV[0][g] = __builtin_amdgcn_mfma_f32_16x16x32_bf16(af0, bV0[ks], accV[0][g], 0, 0, 0);
                accU[1][g] = __builtin_amdgcn_mfma_f32_16x16x32_bf16(af1, bU0[ks], accU[1][g], 0, 0, 0);
                accV[1][g] = __builtin_amdgcn_mfma_f32_16x16x32_bf16(af1, bV0[ks], accV[1][g], 0, 0, 0);
                accU[2][g] = __builtin_amdgcn_mfma_f32_16x16x32_bf16(af2, bU0[ks], accU[2][g], 0, 0, 0);
                accV[2][g] = __builtin_amdgcn_mfma_f32_16x16x32_bf16(af2, bV0[ks], accV[2][g], 0, 0, 0);
                __builtin_amdgcn_s_setprio(0);
            }
        }
#pragma unroll
        for (int g = 0; g < 2; g++) {
            float nv[4];
#pragma unroll
            for (int j = 0; j < 4; j++) {
                dotv[0][g][j] = accU[0][g][j] * accV[0][g][j] + accU[1][g][j] * accV[1][g][j]
                              + accU[2][g][j] * accV[2][g][j];
                nv[j] = sqrtf(accV[0][g][j] * accV[0][g][j] + accV[1][g][j] * accV[1][g][j]
                            + accV[2][g][j] * accV[2][g][j] + 1e-8f);
            }
            nvp[0][g][0] = pk2(nv[0], nv[1]);
            nvp[0][g][1] = pk2(nv[2], nv[3]);
#pragma unroll
            for (int d = 0; d < 3; d++) {
                uvh[0][d][g][0] = pk2(accU[d][g][0], accU[d][g][1]);
                uvh[0][d][g][1] = pk2(accU[d][g][2], accU[d][g][3]);
            }
        }
    }

    // ---- p2 cf=0 panel burst (hides under p1 cf=1 compute) ----
    short8 w0p[16];
#pragma unroll
    for (int ks = 0; ks < 16; ks++) w0p[ks] = PW1[(size_t)((w * 2) * 16 + ks) * 64 + l];

    // ---- phase 1, cf = 1 ----
    {
        floatx4 accU[3][2], accV[3][2];
#pragma unroll
        for (int d = 0; d < 3; d++)
#pragma unroll
            for (int g = 0; g < 2; g++) { accU[d][g] = (floatx4)0.f; accV[d][g] = (floatx4)0.f; }
#pragma unroll
        for (int ks = 0; ks < 8; ks++) {
#pragma unroll
            for (int g = 0; g < 2; g++) {
                short8 af0 = *(const short8*)(LB + ((g * 24 + 0 * 8 + ks) << 10) + loff);
                short8 af1 = *(const short8*)(LB + ((g * 24 + 1 * 8 + ks) << 10) + loff);
                short8 af2 = *(const short8*)(LB + ((g * 24 + 2 * 8 + ks) << 10) + loff);
                __builtin_amdgcn_s_setprio(1);
                accU[0][g] = __builtin_amdgcn_mfma_f32_16x16x32_bf16(af0, bU1[ks], accU[0][g], 0, 0, 0);
                accV[0][g] = __builtin_amdgcn_mfma_f32_16x16x32_bf16(af0, bV1[ks], accV[0][g], 0, 0, 0);
                accU[1][g] = __builtin_amdgcn_mfma_f32_16x16x32_bf16(af1, bU1[ks], accU[1][g], 0, 0, 0);
                accV[1][g] = __builtin_amdgcn_mfma_f32_16x16x32_bf16(af1, bV1[ks], accV[1][g], 0, 0, 0);
                accU[2][g] = __builtin_amdgcn_mfma_f32_16x16x32_bf16(af2, bU1[ks], accU[2][g], 0, 0, 0);
                accV[2][g] = __builtin_amdgcn_mfma_f32_16x16x32_bf16(af2, bV1[ks], accV[2][g], 0, 0, 0);
                __builtin_amdgcn_s_setprio(0);
            }
        }
#pragma unroll
        for (int g = 0; g < 2; g++) {
            float nv[4];
#pragma unroll
            for (int j = 0; j < 4; j++) {
                dotv[1][g][j] = accU[0][g][j] * accV[0][g][j] + accU[1][g][j] * accV[1][g][j]
                              + accU[2][g][j] * accV[2][g][j];
                nv[j] = sqrtf(accV[0][g][j] * accV[0][g][j] + accV[1][g][j] * accV[1][g][j]
                            + accV[2][g][j] * accV[2][g][j] + 1e-8f);
            }
            nvp[1][g][0] = pk2(nv[0], nv[1]);
            nvp[1][g][1] = pk2(nv[2], nv[3]);
#pragma unroll
            for (int d = 0; d < 3; d++) {
                uvh[1][d][g][0] = pk2(accU[d][g][0], accU[d][g][1]);
                uvh[1][d][g][1] = pk2(accU[d][g][2], accU[d][g][3]);
            }
        }
    }

    BAR();  // B2: all v-frag reads done -> slotX/slotY writable

    // ---- Vv_norm -> slotX frags ----
#pragma unroll
    for (int cf = 0; cf < 2; cf++) {
        int kp = (cf << 1) | (l15 >> 3);
        int cb = (l15 & 7) << 1;
#pragma unroll
        for (int g = 0; g < 2; g++)
#pragma unroll
            for (int j = 0; j < 4; j++) {
                int a15 = (lhi << 2) + j;
                unsigned short hbits = (unsigned short)((j & 1) ? (nvp[cf][g][j >> 1] >> 16)
                                                                : (nvp[cf][g][j >> 1] & 0xFFFF));
                int bo = ((g * 8 + w) << 10) + (kp << 8) + ((a15 ^ kp) << 4) + cb;
                *(unsigned short*)(LB + bo) = hbits;
            }
    }

    // ---- p2 cf=1 panel burst ----
    short8 w1p[16];
#pragma unroll
    for (int ks = 0; ks < 16; ks++) w1p[ks] = PW1[(size_t)((w * 2 + 1) * 16 + ks) * 64 + l];

    BAR();  // B3: norm frags visible

    // ---- phase 2, cf = 0 ----
    {
        floatx4 acc2[2];
        acc2[0] = (floatx4)0.f; acc2[1] = (floatx4)0.f;
#pragma unroll
        for (int ks2 = 0; ks2 < 16; ks2++) {
            short8 af0 = (ks2 < 8)
                ? *(const short8*)(LB + 49152 + ((0 * 8 + ks2) << 10) + loff)
                : *(const short8*)(LB + ((0 * 8 + ks2 - 8) << 10) + loff);
            short8 af1 = (ks2 < 8)
                ? *(const short8*)(LB + 49152 + ((1 * 8 + ks2) << 10) + loff)
                : *(const short8*)(LB + ((1 * 8 + ks2 - 8) << 10) + loff);
            __builtin_amdgcn_s_setprio(1);
            acc2[0] = __builtin_amdgcn_mfma_f32_16x16x32_bf16(af0, w0p[ks2], acc2[0], 0, 0, 0);
            acc2[1] = __builtin_amdgcn_mfma_f32_16x16x32_bf16(af1, w0p[ks2], acc2[1], 0, 0, 0);
            __builtin_amdgcn_s_setprio(0);
        }
        int c = (w << 5) + l15;
        float bb = b1[c];
        int kp = (l15 >> 3);
        int cb = (l15 & 7) << 1;
#pragma unroll
        for (int g = 0; g < 2; g++)
#pragma unroll
            for (int j = 0; j < 4; j++) {
                int a15 = (lhi << 2) + j;
                float x = acc2[g][j] + bb;
                float hh = x / (1.f + __expf(-x));
                int bo = 16384 + ((g * 8 + w) << 10) + (kp << 8) + ((a15 ^ kp) << 4) + cb;
                *(unsigned short*)(LB + bo) = f2bf(hh);
            }
    }

    // ---- p3 sv panel burst (hides under p2 cf=1) ----
    short8 psv[16];
#pragma unroll
    for (int q = 0; q < 16; q++) {
        int cfq = q >> 3, ksq = q & 7;
        psv[q] = PW2[(size_t)((16 + w * 2 + cfq) * 8 + ksq) * 64 + l];
    }

    // ---- phase 2, cf = 1 ----
    {
        floatx4 acc2[2];
        acc2[0] = (floatx4)0.f; acc2[1] = (floatx4)0.f;
#pragma unroll
        for (int ks2 = 0; ks2 < 16; ks2++) {
            short8 af0 = (ks2 < 8)
                ? *(const short8*)(LB + 49152 + ((0 * 8 + ks2) << 10) + loff)
                : *(const short8*)(LB + ((0 * 8 + ks2 - 8) << 10) + loff);
            short8 af1 = (ks2 < 8)
                ? *(const short8*)(LB + 49152 + ((1 * 8 + ks2) << 10) + loff)
                : *(const short8*)(LB + ((1 * 8 + ks2 - 8) << 10) + loff);
            __builtin_amdgcn_s_setprio(1);
            acc2[0] = __builtin_amdgcn_mfma_f32_16x16x32_bf16(af0, w1p[ks2], acc2[0], 0, 0, 0);
            acc2[1] = __builtin_amdgcn_mfma_f32_16x16x32_bf16(af1, w1p[ks2], acc2[1], 0, 0, 0);
            __builtin_amdgcn_s_setprio(0);
        }
        int c = (w << 5) + 16 + l15;
        float bb = b1[c];
        int kp = 2 | (l15 >> 3);
        int cb = (l15 & 7) << 1;
#pragma unroll
        for (int g = 0; g < 2; g++)
#pragma unroll
            for (int j = 0; j < 4; j++) {
                int a15 = (lhi << 2) + j;
                float x = acc2[g][j] + bb;
                float hh = x / (1.f + __expf(-x));
                int bo = 16384 + ((g * 8 + w) << 10) + (kp << 8) + ((a15 ^ kp) << 4) + cb;
                *(unsigned short*)(LB + bo) = f2bf(hh);
            }
    }

    // ---- p3 ss panel burst ----
    short8 pss[16];
#pragma unroll
    for (int q = 0; q < 16; q++) {
        int cfq = q >> 3, ksq = q & 7;
        pss[q] = PW2[(size_t)((0 + w * 2 + cfq) * 8 + ksq) * 64 + l];
    }

    BAR();  // B4: hid visible

    // ---- phase 3: per-segment passes sv -> ss -> vv (panels pre-loaded) ----
    float svd[2][2][4];   // sv*dot -> sdelta -> a_vv (reused)
    {   // sv (sg=1), uses psv
        floatx4 acc[2][2];
#pragma unroll
        for (int g = 0; g < 2; g++) { acc[g][0] = (floatx4)0.f; acc[g][1] = (floatx4)0.f; }
#pragma unroll
        for (int ks3 = 0; ks3 < 8; ks3++) {
            short8 af0 = *(const short8*)(LB + 16384 + ((0 * 8 + ks3) << 10) + loff);
            short8 af1 = *(const short8*)(LB + 16384 + ((1 * 8 + ks3) << 10) + loff);
            __builtin_amdgcn_s_setprio(1);
            acc[0][0] = __builtin_amdgcn_mfma_f32_16x16x32_bf16(af0, psv[ks3], acc[0][0], 0, 0, 0);
            acc[0][1] = __builtin_amdgcn_mfma_f32_16x16x32_bf16(af0, psv[8 + ks3], acc[0][1], 0, 0, 0);
            acc[1][0] = __builtin_amdgcn_mfma_f32_16x16x32_bf16(af1, psv[ks3], acc[1][0], 0, 0, 0);
            acc[1][1] = __builtin_amdgcn_mfma_f32_16x16x32_bf16(af1, psv[8 + ks3], acc[1][1], 0, 0, 0);
            __builtin_amdgcn_s_setprio(0);
        }
#pragma unroll
        for (int cf = 0; cf < 2; cf++) {
            float bsv = b2[256 + (w << 5) + (cf << 4) + l15];
#pragma unroll
            for (int g = 0; g < 2; g++)
#pragma unroll
                for (int j = 0; j < 4; j++)
                    svd[cf][g][j] = (acc[g][cf][j] + bsv) * dotv[cf][g][j];
        }
    }

    // ---- p3 vv panel burst (hides under ss compute) ----
    short8 pvv[16];
#pragma unroll
    for (int q = 0; q < 16; q++) {
        int cfq = q >> 3, ksq = q & 7;
        pvv[q] = PW2[(size_t)((32 + w * 2 + cfq) * 8 + ksq) * 64 + l];
    }

    {   // ss (sg=0), uses pss
        floatx4 acc[2][2];
#pragma unroll
        for (int g = 0; g < 2; g++) { acc[g][0] = (floatx4)0.f; acc[g][1] = (floatx4)0.f; }
#pragma unroll
        for (int ks3 = 0; ks3 < 8; ks3++) {
            short8 af0 = *(const short8*)(LB + 16384 + ((0 * 8 + ks3) << 10) + loff);
            short8 af1 = *(const short8*)(LB + 16384 + ((1 * 8 + ks3) << 10) + loff);
            __builtin_amdgcn_s_setprio(1);
            acc[0][0] = __builtin_amdgcn_mfma_f32_16x16x32_bf16(af0, pss[ks3], acc[0][0], 0, 0, 0);
            acc[0][1] = __builtin_amdgcn_mfma_f32_16x16x32_bf16(af0, pss[8 + ks3], acc[0][1], 0, 0, 0);
            acc[1][0] = __builtin_amdgcn_mfma_f32_16x16x32_bf16(af1, pss[ks3], acc[1][0], 0, 0, 0);
            acc[1][1] = __builtin_amdgcn_mfma_f32_16x16x32_bf16(af1, pss[8 + ks3], acc[1][1], 0, 0, 0);
            __builtin_amdgcn_s_setprio(0);
        }
        // sdelta = (ss+bss) + sv*dot -> slotX [a][c]
#pragma unroll
        for (int cf = 0; cf < 2; cf++) {
            int c = (w << 5) + (cf << 4) + l15;
            float bss = b2[c];
#pragma unroll
            for (int g = 0; g < 2; g++)
#pragma unroll
                for (int j = 0; j < 4; j++) {
                    int a = (g << 4) + (lhi << 2) + j;
                    float sd = (acc[g][cf][j] + bss) + svd[cf][g][j];
                    int bo = ((a << 9) + (c << 1)) ^ ((a & 7) << 4);
                    *(unsigned short*)(LB + bo) = f2bf(sd);
                }
        }
    }
    {   // vv (sg=2), uses pvv -> a_vv kept in regs (svd reused)
        floatx4 acc[2][2];
#pragma unroll
        for (int g = 0; g < 2; g++) { acc[g][0] = (floatx4)0.f; acc[g][1] = (floatx4)0.f; }
#pragma unroll
        for (int ks3 = 0; ks3 < 8; ks3++) {
            short8 af0 = *(const short8*)(LB + 16384 + ((0 * 8 + ks3) << 10) + loff);
            short8 af1 = *(const short8*)(LB + 16384 + ((1 * 8 + ks3) << 10) + loff);
            __builtin_amdgcn_s_setprio(1);
            acc[0][0] = __builtin_amdgcn_mfma_f32_16x16x32_bf16(af0, pvv[ks3], acc[0][0], 0, 0, 0);
            acc[0][1] = __builtin_amdgcn_mfma_f32_16x16x32_bf16(af0, pvv[8 + ks3], acc[0][1], 0, 0, 0);
            acc[1][0] = __builtin_amdgcn_mfma_f32_16x16x32_bf16(af1, pvv[ks3], acc[1][0], 0, 0, 0);
            acc[1][1] = __builtin_amdgcn_mfma_f32_16x16x32_bf16(af1, pvv[8 + ks3], acc[1][1], 0, 0, 0);
            __builtin_amdgcn_s_setprio(0);
        }
#pragma unroll
        for (int cf = 0; cf < 2; cf++) {
            float bvv = b2[512 + (w << 5) + (cf << 4) + l15];
#pragma unroll
            for (int g = 0; g < 2; g++)
#pragma unroll
                for (int j = 0; j < 4; j++)
                    svd[cf][g][j] = acc[g][cf][j] + bvv;
        }
    }

    BAR();  // B5: sdelta visible

    // ---- epilogue: s_out (LN map; raw s from regs; 256B contiguous) ----
    {
        size_t gb = (size_t)(atom0 + aLN) * H;
        int xo = (aLN & 7) << 4;
#pragma unroll
        for (int i = 0; i < 4; i++) {
            int chunk = lg + (i << 4);
            short4v sd4 = *(const short4v*)(LB + (((aLN << 9) + (chunk << 3)) ^ xo));
            floatx4 o;
#pragma unroll
            for (int j = 0; j < 4; j++) o[j] = bf2f((unsigned short)srp[i][j]) + bf2f((unsigned short)sd4[j]);
            *(floatx4*)(s_out + gb + chunk * 4) = o;
        }
    }

    // ---- epilogue: v_out = v + a_vv * Uv. cf INNER so both 64B halves of
    //      each 128B line are written back-to-back (kills half-dirty
    //      evictions that doubled WRITE traffic). Tail overlaps next block.
#pragma unroll
    for (int g = 0; g < 2; g++)
#pragma unroll
        for (int j = 0; j < 4; j++) {
            int a = (g << 4) + (lhi << 2) + j;
            size_t base = (size_t)(atom0 + a) * 3 * H + (w << 5) + l15;
#pragma unroll
            for (int d = 0; d < 3; d++) {
                size_t rowb = base + (size_t)d * H;
#pragma unroll
                for (int cf = 0; cf < 2; cf++) {
                    size_t vi = rowb + (cf << 4);
                    float uv = upk(uvh[cf][d][g][j >> 1], j & 1);
                    v_out[vi] = v[vi] + svd[cf][g][j] * uv;
                }
            }
        }
}

extern "C" void kernel_launch(void* const* d_in, const int* in_sizes, int n_in,
                              void* d_out, int out_size, void* d_ws, size_t ws_size,
                              hipStream_t stream) {
    const float* s     = (const float*)d_in[0];
    const float* v     = (const float*)d_in[1];
    const float* gamma = (const float*)d_in[2];
    const float* beta  = (const float*)d_in[3];
    const float* U_W   = (const float*)d_in[4];
    const float* V_W   = (const float*)d_in[5];
    const float* W1    = (const float*)d_in[6];
    const float* b1    = (const float*)d_in[7];
    const float* W2    = (const float*)d_in[8];
    const float* b2    = (const float*)d_in[9];
    float* s_out = (float*)d_out;
    float* v_out = s_out + (size_t)NATOMS * H;
    unsigned short* P = (unsigned short*)d_ws;   // needs 917504 B

    pack_weights<<<dim3(224), dim3(256), 0, stream>>>(U_W, V_W, W1, W2, P);
    painn_main<<<dim3(NBLK), dim3(512), 0, stream>>>(s, v, gamma, beta, b1, b2, P, s_out, v_out);
}

// Round 16
// 416.348 us; speedup vs baseline: 2.9661x; 2.9661x over previous
//
#include <hip/hip_runtime.h>
#include <stdint.h>

#define H 256
#define NATOMS 100000
#define MB 32
#define NBLK (NATOMS / MB)   // 3125

typedef float floatx4 __attribute__((ext_vector_type(4)));
typedef short short8 __attribute__((ext_vector_type(8)));
typedef short short4v __attribute__((ext_vector_type(4)));

// lgkm-only barrier: global prefetches stay in flight across it.
#define BAR() do { asm volatile("s_waitcnt lgkmcnt(0)\n\ts_barrier" ::: "memory"); __builtin_amdgcn_sched_barrier(0); } while (0)

__device__ __forceinline__ unsigned short f2bf(float x) {
    union { float f; uint32_t u; } c; c.f = x;
    return (unsigned short)((c.u + 0x7FFFu + ((c.u >> 16) & 1u)) >> 16);
}
__device__ __forceinline__ float bf2f(unsigned short h) {
    union { uint32_t u; float f; } c; c.u = ((uint32_t)h) << 16; return c.f;
}
__device__ __forceinline__ uint32_t pk2(float lo, float hi) {
    return (uint32_t)f2bf(lo) | ((uint32_t)f2bf(hi) << 16);
}
__device__ __forceinline__ float upk(uint32_t u, int hi) {
    union { uint32_t u; float f; } c;
    c.u = hi ? (u & 0xFFFF0000u) : (u << 16);
    return c.f;
}

// ---------------------------------------------------------------------------
// Pack weights (f32 [K][N] row-major) into bf16 MFMA-B-fragment order.
// frag fl = nb*(K/32)+kb; lane l holds W[kb*32+(l>>4)*8+e][nb*16+(l&15)].
// ws layout (bf16 elems): U@0, V@65536, W1@131072, W2@262144 (896KB total).
// ---------------------------------------------------------------------------
__global__ void pack_weights(const float* __restrict__ U_W, const float* __restrict__ V_W,
                             const float* __restrict__ W1, const float* __restrict__ W2,
                             unsigned short* __restrict__ P) {
    int gtid = blockIdx.x * 256 + threadIdx.x;
    int fid = gtid >> 6, l = gtid & 63;
    const float* src; int K, N, fl; unsigned short* dst;
    if (fid < 128)      { src = U_W; K = 256; N = 256; fl = fid;       dst = P; }
    else if (fid < 256) { src = V_W; K = 256; N = 256; fl = fid - 128; dst = P + 65536; }
    else if (fid < 512) { src = W1;  K = 512; N = 256; fl = fid - 256; dst = P + 131072; }
    else                { src = W2;  K = 256; N = 768; fl = fid - 512; dst = P + 262144; }
    int kbc = K >> 5;
    int nb = fl / kbc, kb = fl - nb * kbc;
    int k0 = kb * 32 + ((l >> 4) << 3);
    int n0 = nb * 16 + (l & 15);
    short8 outv;
#pragma unroll
    for (int e = 0; e < 8; e++) outv[e] = (short)f2bf(src[(size_t)(k0 + e) * N + n0]);
    *(short8*)(dst + (size_t)fl * 512 + l * 8) = outv;
}

// ---------------------------------------------------------------------------
// Fused PaiNN mixing (R8 structure + depth-4 B prefetch rings + line-paired
// v_out). Block = 32 atoms, 512 thr (8 waves), LDS 64KB -> 2 blocks/CU.
// VGPR cap at 4 waves/SIMD = 128/wave (R15 lesson: NOT 512); depth-4 rings
// add only +16/+8/+16 VGPR (peak ~110). Ring q runs ACROSS cf/segment passes
// so pass boundaries stay covered; 3 outstanding loads cover ~390cyc > L2.
// Wave w owns cols [32w,32w+32) (cf 0..1). A-frags 1KB MFMA-linear w/
// kpos-XOR swizzle; lane read off loff = (l>>4)*256 + ((l15^(l>>4))<<4).
// LDS map: [0,48K) v-frags; post-B2 [0,16K) Vv_norm->sdelta, [16,32K) hid;
// [48,64K) LNf s_norm frags. Regs: raw s, Uv, dotv, a_vv.
// ---------------------------------------------------------------------------
__global__ __launch_bounds__(512, 4) void painn_main(
    const float* __restrict__ s, const float* __restrict__ v,
    const float* __restrict__ gamma, const float* __restrict__ beta,
    const float* __restrict__ b1, const float* __restrict__ b2,
    const unsigned short* __restrict__ P,
    float* __restrict__ s_out, float* __restrict__ v_out) {

    __shared__ unsigned short SH[32768];   // 64KB
    char* LB = (char*)SH;

    const int tid = threadIdx.x;
    const int w = tid >> 6, l = tid & 63;
    const int l15 = l & 15, lhi = l >> 4;
    const int loff = (lhi << 8) | ((l15 ^ lhi) << 4);
    const int atom0 = blockIdx.x * MB;
    const int aLN = tid >> 4, lg = tid & 15;          // 16 lanes per atom
    const int gLN = aLN >> 4, a15LN = aLN & 15;

    const short8* PU  = (const short8*)P;
    const short8* PV  = (const short8*)(P + 65536);
    const short8* PW1 = (const short8*)(P + 131072);
    const short8* PW2 = (const short8*)(P + 262144);

    // ---- stage v -> v-frags [0,48K) ----
    {
        const floatx4* vsrc = (const floatx4*)(v + (size_t)atom0 * 3 * H);
#pragma unroll
        for (int i = 0; i < 6; i++) {
            int p = i * 512 + tid;
            int a = p / 96, rem = p - a * 96;
            int d = rem >> 5, c8 = rem & 31;
            int q = ((a * 3 + d) << 6) + (c8 << 1);
            floatx4 x0 = vsrc[q], x1 = vsrc[q + 1];
            short8 pk;
#pragma unroll
            for (int j = 0; j < 4; j++) { pk[j] = (short)f2bf(x0[j]); pk[4 + j] = (short)f2bf(x1[j]); }
            int ks = c8 >> 2, kpos = c8 & 3;
            int bo = ((((a >> 4) * 24) + d * 8 + ks) << 10) + (kpos << 8) + (((a & 15) ^ kpos) << 4);
            *(short8*)(LB + bo) = pk;
        }
    }

    // ---- LayerNorm(s) -> LNf frags [48K,64K); raw s packed in regs ----
    short4v srp[4];
    {
        const floatx4* srow = (const floatx4*)(s + (size_t)(atom0 + aLN) * H);
        floatx4 vals[4];
        float sum = 0.f, sq = 0.f;
#pragma unroll
        for (int i = 0; i < 4; i++) {
            vals[i] = srow[lg + (i << 4)];
#pragma unroll
            for (int j = 0; j < 4; j++) { sum += vals[i][j]; sq += vals[i][j] * vals[i][j]; }
        }
#pragma unroll
        for (int m = 1; m < 16; m <<= 1) { sum += __shfl_xor(sum, m); sq += __shfl_xor(sq, m); }
        float mu = sum * (1.f / 256.f);
        float var = sq * (1.f / 256.f) - mu * mu;
        float rs = rsqrtf(var + 1e-5f);
#pragma unroll
        for (int i = 0; i < 4; i++) {
            int chunk = lg + (i << 4);
            floatx4 g4 = *(const floatx4*)(gamma + chunk * 4);
            floatx4 be4 = *(const floatx4*)(beta + chunk * 4);
            short4v pk, pr;
#pragma unroll
            for (int j = 0; j < 4; j++) {
                pk[j] = (short)f2bf((vals[i][j] - mu) * rs * g4[j] + be4[j]);
                pr[j] = (short)f2bf(vals[i][j]);
            }
            srp[i] = pr;
            int ks2 = chunk >> 3, kpos = (chunk >> 1) & 3, half = chunk & 1;
            int bo = 49152 + ((gLN * 8 + ks2) << 10) + (kpos << 8) + ((a15LN ^ kpos) << 4) + half * 8;
            *(short4v*)(LB + bo) = pk;
        }
    }

    // ---- p1 ring preload (slots 0..2) before barrier ----
    short8 bU[4], bV[4];
#pragma unroll
    for (int q = 0; q < 3; q++) {
        bU[q] = PU[(size_t)((w * 2) * 8 + q) * 64 + l];
        bV[q] = PV[(size_t)((w * 2) * 8 + q) * 64 + l];
    }

    BAR();  // B1: v-frags + LNf visible (vmcnt NOT drained)

    // ---- phase 1: Uv & Vv, per-cf passes; unified ring q = cf*8+ks ----
    float dotv[2][2][4];
    uint32_t uvh[2][3][2][2];   // [cf][d][g][pair] packed bf16
    uint32_t nvp[2][2][2];      // [cf][g][pair]   packed bf16
#pragma unroll
    for (int cf = 0; cf < 2; cf++) {
        floatx4 accU[3][2], accV[3][2];
#pragma unroll
        for (int d = 0; d < 3; d++)
#pragma unroll
            for (int g = 0; g < 2; g++) { accU[d][g] = (floatx4)0.f; accV[d][g] = (floatx4)0.f; }
#pragma unroll
        for (int ks = 0; ks < 8; ks++) {
            const int q = cf * 8 + ks;
            if (q + 3 < 16) {
                const int m = q + 3;
                const int nbm = w * 2 + (m >> 3), fr = m & 7;
                bU[m & 3] = PU[(size_t)(nbm * 8 + fr) * 64 + l];
                bV[m & 3] = PV[(size_t)(nbm * 8 + fr) * 64 + l];
            }
#pragma unroll
            for (int g = 0; g < 2; g++) {
                short8 af0 = *(const short8*)(LB + ((g * 24 + 0 * 8 + ks) << 10) + loff);
                short8 af1 = *(const short8*)(LB + ((g * 24 + 1 * 8 + ks) << 10) + loff);
                short8 af2 = *(const short8*)(LB + ((g * 24 + 2 * 8 + ks) << 10) + loff);
                __builtin_amdgcn_s_setprio(1);
                accU[0][g] = __builtin_amdgcn_mfma_f32_16x16x32_bf16(af0, bU[q & 3], accU[0][g], 0, 0, 0);
                accV[0][g] = __builtin_amdgcn_mfma_f32_16x16x32_bf16(af0, bV[q & 3], accV[0][g], 0, 0, 0);
                accU[1][g] = __builtin_amdgcn_mfma_f32_16x16x32_bf16(af1, bU[q & 3], accU[1][g], 0, 0, 0);
                accV[1][g] = __builtin_amdgcn_mfma_f32_16x16x32_bf16(af1, bV[q & 3], accV[1][g], 0, 0, 0);
                accU[2][g] = __builtin_amdgcn_mfma_f32_16x16x32_bf16(af2, bU[q & 3], accU[2][g], 0, 0, 0);
                accV[2][g] = __builtin_amdgcn_mfma_f32_16x16x32_bf16(af2, bV[q & 3], accV[2][g], 0, 0, 0);
                __builtin_amdgcn_s_setprio(0);
            }
        }
        // fold: dot_uv, ||Vv||, pack Uv -> bf16
#pragma unroll
        for (int g = 0; g < 2; g++) {
            float nv[4];
#pragma unroll
            for (int j = 0; j < 4; j++) {
                dotv[cf][g][j] = accU[0][g][j] * accV[0][g][j] + accU[1][g][j] * accV[1][g][j]
                               + accU[2][g][j] * accV[2][g][j];
                nv[j] = sqrtf(accV[0][g][j] * accV[0][g][j] + accV[1][g][j] * accV[1][g][j]
                            + accV[2][g][j] * accV[2][g][j] + 1e-8f);
            }
            nvp[cf][g][0] = pk2(nv[0], nv[1]);
            nvp[cf][g][1] = pk2(nv[2], nv[3]);
#pragma unroll
            for (int d = 0; d < 3; d++) {
                uvh[cf][d][g][0] = pk2(accU[d][g][0], accU[d][g][1]);
                uvh[cf][d][g][1] = pk2(accU[d][g][2], accU[d][g][3]);
            }
        }
    }

    BAR();  // B2: all v-frag reads done -> slotX/slotY writable

    // ---- Vv_norm -> slotX frags ----
#pragma unroll
    for (int cf = 0; cf < 2; cf++) {
        int kp = (cf << 1) | (l15 >> 3);
        int cb = (l15 & 7) << 1;
#pragma unroll
        for (int g = 0; g < 2; g++)
#pragma unroll
            for (int j = 0; j < 4; j++) {
                int a15 = (lhi << 2) + j;
                unsigned short hbits = (unsigned short)((j & 1) ? (nvp[cf][g][j >> 1] >> 16)
                                                                : (nvp[cf][g][j >> 1] & 0xFFFF));
                int bo = ((g * 8 + w) << 10) + (kp << 8) + ((a15 ^ kp) << 4) + cb;
                *(unsigned short*)(LB + bo) = hbits;
            }
    }

    // ---- p2 ring preload (slots 0..2) ----
    short8 bw[4];
#pragma unroll
    for (int q = 0; q < 3; q++) bw[q] = PW1[(size_t)((w * 2) * 16 + q) * 64 + l];

    BAR();  // B3: norm frags visible

    // ---- phase 2: hid = silu(ctx_in @ W1 + b1); unified ring q = cf*16+ks ----
#pragma unroll
    for (int cf = 0; cf < 2; cf++) {
        floatx4 acc2[2];
        acc2[0] = (floatx4)0.f; acc2[1] = (floatx4)0.f;
#pragma unroll
        for (int ks2 = 0; ks2 < 16; ks2++) {
            const int q = cf * 16 + ks2;
            if (q + 3 < 32) {
                const int m = q + 3;
                const int nbm = w * 2 + (m >> 4), fr = m & 15;
                bw[m & 3] = PW1[(size_t)(nbm * 16 + fr) * 64 + l];
            }
            short8 af0 = (ks2 < 8)
                ? *(const short8*)(LB + 49152 + ((0 * 8 + ks2) << 10) + loff)
                : *(const short8*)(LB + ((0 * 8 + ks2 - 8) << 10) + loff);
            short8 af1 = (ks2 < 8)
                ? *(const short8*)(LB + 49152 + ((1 * 8 + ks2) << 10) + loff)
                : *(const short8*)(LB + ((1 * 8 + ks2 - 8) << 10) + loff);
            __builtin_amdgcn_s_setprio(1);
            acc2[0] = __builtin_amdgcn_mfma_f32_16x16x32_bf16(af0, bw[q & 3], acc2[0], 0, 0, 0);
            acc2[1] = __builtin_amdgcn_mfma_f32_16x16x32_bf16(af1, bw[q & 3], acc2[1], 0, 0, 0);
            __builtin_amdgcn_s_setprio(0);
        }
        // hid -> slotY frags (slotY free since B2; readers gated by B4)
        int c = (w << 5) + (cf << 4) + l15;
        float bb = b1[c];
        int kp = (cf << 1) | (l15 >> 3);
        int cb = (l15 & 7) << 1;
#pragma unroll
        for (int g = 0; g < 2; g++)
#pragma unroll
            for (int j = 0; j < 4; j++) {
                int a15 = (lhi << 2) + j;
                float x = acc2[g][j] + bb;
                float hh = x / (1.f + __expf(-x));
                int bo = 16384 + ((g * 8 + w) << 10) + (kp << 8) + ((a15 ^ kp) << 4) + cb;
                *(unsigned short*)(LB + bo) = f2bf(hh);
            }
    }

    // ---- p3 ring preload (slots 0..2 of sv segment) ----
    short8 b2w[4][2];
#pragma unroll
    for (int q = 0; q < 3; q++) {
        b2w[q][0] = PW2[(size_t)((16 + w * 2 + 0) * 8 + q) * 64 + l];
        b2w[q][1] = PW2[(size_t)((16 + w * 2 + 1) * 8 + q) * 64 + l];
    }

    BAR();  // B4: hid visible

    // ---- phase 3: segment passes sv -> ss -> vv; unified ring q = sg*8+ks ----
    // segment base table: q>>3 = 0 -> sv(16), 1 -> ss(0), 2 -> vv(32)
    float svd[2][2][4];   // sv*dot -> sdelta -> a_vv (reused)
#pragma unroll
    for (int sg = 0; sg < 3; sg++) {
        floatx4 acc[2][2];
#pragma unroll
        for (int g = 0; g < 2; g++) { acc[g][0] = (floatx4)0.f; acc[g][1] = (floatx4)0.f; }
#pragma unroll
        for (int ks3 = 0; ks3 < 8; ks3++) {
            const int q = sg * 8 + ks3;
            if (q + 3 < 24) {
                const int m = q + 3;
                const int sb = ((m >> 3) == 0) ? 16 : (((m >> 3) == 1) ? 0 : 32);
                const int fr = m & 7;
                b2w[m & 3][0] = PW2[(size_t)((sb + w * 2 + 0) * 8 + fr) * 64 + l];
                b2w[m & 3][1] = PW2[(size_t)((sb + w * 2 + 1) * 8 + fr) * 64 + l];
            }
            short8 af0 = *(const short8*)(LB + 16384 + ((0 * 8 + ks3) << 10) + loff);
            short8 af1 = *(const short8*)(LB + 16384 + ((1 * 8 + ks3) << 10) + loff);
            __builtin_amdgcn_s_setprio(1);
            acc[0][0] = __builtin_amdgcn_mfma_f32_16x16x32_bf16(af0, b2w[q & 3][0], acc[0][0], 0, 0, 0);
            acc[0][1] = __builtin_amdgcn_mfma_f32_16x16x32_bf16(af0, b2w[q & 3][1], acc[0][1], 0, 0, 0);
            acc[1][0] = __builtin_amdgcn_mfma_f32_16x16x32_bf16(af1, b2w[q & 3][0], acc[1][0], 0, 0, 0);
            acc[1][1] = __builtin_amdgcn_mfma_f32_16x16x32_bf16(af1, b2w[q & 3][1], acc[1][1], 0, 0, 0);
            __builtin_amdgcn_s_setprio(0);
        }
        if (sg == 0) {          // sv fold
#pragma unroll
            for (int cf = 0; cf < 2; cf++) {
                float bsv = b2[256 + (w << 5) + (cf << 4) + l15];
#pragma unroll
                for (int g = 0; g < 2; g++)
#pragma unroll
                    for (int j = 0; j < 4; j++)
                        svd[cf][g][j] = (acc[g][cf][j] + bsv) * dotv[cf][g][j];
            }
        } else if (sg == 1) {   // ss fold -> sdelta into slotX
#pragma unroll
            for (int cf = 0; cf < 2; cf++) {
                int c = (w << 5) + (cf << 4) + l15;
                float bss = b2[c];
#pragma unroll
                for (int g = 0; g < 2; g++)
#pragma unroll
                    for (int j = 0; j < 4; j++) {
                        int a = (g << 4) + (lhi << 2) + j;
                        float sd = (acc[g][cf][j] + bss) + svd[cf][g][j];
                        int bo = ((a << 9) + (c << 1)) ^ ((a & 7) << 4);
                        *(unsigned short*)(LB + bo) = f2bf(sd);
                    }
            }
        } else {                // vv fold -> a_vv in regs
#pragma unroll
            for (int cf = 0; cf < 2; cf++) {
                float bvv = b2[512 + (w << 5) + (cf << 4) + l15];
#pragma unroll
                for (int g = 0; g < 2; g++)
#pragma unroll
                    for (int j = 0; j < 4; j++)
                        svd[cf][g][j] = acc[g][cf][j] + bvv;
            }
        }
    }

    BAR();  // B5: sdelta visible

    // ---- epilogue: s_out (LN map; raw s from regs; 256B contiguous) ----
    {
        size_t gb = (size_t)(atom0 + aLN) * H;
        int xo = (aLN & 7) << 4;
#pragma unroll
        for (int i = 0; i < 4; i++) {
            int chunk = lg + (i << 4);
            short4v sd4 = *(const short4v*)(LB + (((aLN << 9) + (chunk << 3)) ^ xo));
            floatx4 o;
#pragma unroll
            for (int j = 0; j < 4; j++) o[j] = bf2f((unsigned short)srp[i][j]) + bf2f((unsigned short)sd4[j]);
            *(floatx4*)(s_out + gb + chunk * 4) = o;
        }
    }

    // ---- epilogue: v_out = v + a_vv * Uv. cf INNER: both 64B halves of each
    //      128B line stored back-to-back (fixes half-dirty-line WRITE bloat).
    //      Tail stall overlaps the next block's staging prologue on this CU.
#pragma unroll
    for (int g = 0; g < 2; g++)
#pragma unroll
        for (int j = 0; j < 4; j++) {
            int a = (g << 4) + (lhi << 2) + j;
            size_t base = (size_t)(atom0 + a) * 3 * H + (w << 5) + l15;
#pragma unroll
            for (int d = 0; d < 3; d++) {
                size_t rowb = base + (size_t)d * H;
#pragma unroll
                for (int cf = 0; cf < 2; cf++) {
                    size_t vi = rowb + (cf << 4);
                    float uv = upk(uvh[cf][d][g][j >> 1], j & 1);
                    v_out[vi] = v[vi] + svd[cf][g][j] * uv;
                }
            }
        }
}

extern "C" void kernel_launch(void* const* d_in, const int* in_sizes, int n_in,
                              void* d_out, int out_size, void* d_ws, size_t ws_size,
                              hipStream_t stream) {
    const float* s     = (const float*)d_in[0];
    const float* v     = (const float*)d_in[1];
    const float* gamma = (const float*)d_in[2];
    const float* beta  = (const float*)d_in[3];
    const float* U_W   = (const float*)d_in[4];
    const float* V_W   = (const float*)d_in[5];
    const float* W1    = (const float*)d_in[6];
    const float* b1    = (const float*)d_in[7];
    const float* W2    = (const float*)d_in[8];
    const float* b2    = (const float*)d_in[9];
    float* s_out = (float*)d_out;
    float* v_out = s_out + (size_t)NATOMS * H;
    unsigned short* P = (unsigned short*)d_ws;   // needs 917504 B

    pack_weights<<<dim3(224), dim3(256), 0, stream>>>(U_W, V_W, W1, W2, P);
    painn_main<<<dim3(NBLK), dim3(512), 0, stream>>>(s, v, gamma, beta, b1, b2, P, s_out, v_out);
}